// Round 1
// baseline (696.723 us; speedup 1.0000x reference)
//
#include <hip/hip_runtime.h>
#include <hip/hip_bf16.h>

typedef short bf16x8 __attribute__((ext_vector_type(8)));
typedef float f32x4 __attribute__((ext_vector_type(4)));

#define TILE_M 128
#define TILE_N 128
#define TILE_K 64
#define K_DIM 4096
#define N_DIM 16384
#define M_DIM 2048
#define NSTEP (K_DIM / TILE_K)   // 64

__device__ __forceinline__ unsigned int f2bf(float f) {
    unsigned int u = __builtin_bit_cast(unsigned int, f);
    u += 0x7FFFu + ((u >> 16) & 1u);
    return u >> 16;   // low 16 bits = bf16 (RNE), inputs are finite
}

__device__ __forceinline__ float gelu_tanh(float v) {
    float c = v + 0.044715f * v * v * v;
    float t = tanhf(0.7978845608028654f * c);
    return 0.5f * v * (1.0f + t);
}

__global__ __launch_bounds__(256, 2) void nvfp4_gemm(
    const float* __restrict__ x,
    const int*   __restrict__ wp,
    const float* __restrict__ wscale,
    const float* __restrict__ bias,
    float*       __restrict__ out)
{
    __shared__ uint4  lsA[TILE_M * 8];   // [row][slot] 16B slots, XOR-swizzled
    __shared__ uint4  lsB[TILE_N * 8];
    __shared__ float2 lut[256];          // byte -> (low-nibble val, high-nibble val)

    const int tid = threadIdx.x;

    // ---- decode LUT init (256 threads, 1 entry each) ----
    {
        static const float dectab[16] = {0.f, 0.5f, 1.f, 1.5f, 2.f, 3.f, 4.f, 6.f,
                                         -0.f,-0.5f,-1.f,-1.5f,-2.f,-3.f,-4.f,-6.f};
        int b = tid;
        lut[b] = make_float2(dectab[b & 15], dectab[(b >> 4) & 15]);
    }

    const int bn0 = blockIdx.x * TILE_N;   // N offset
    const int bm0 = blockIdx.y * TILE_M;   // M offset

    const int r = tid >> 1;   // 0..127: row of the tile this thread stages
    const int h = tid & 1;    // which 32-wide K half (one scale block)

    const float4* xp = reinterpret_cast<const float4*>(x + (size_t)(bm0 + r) * K_DIM) + h * 8;
    const uint4*  bp = reinterpret_cast<const uint4*>(wp + (size_t)(bn0 + r) * (K_DIM / 2)) + h * 4;
    const float*  sp = wscale + (size_t)(bn0 + r) * (K_DIM / 32) + h;

    float4 ax[8];
    uint4  bx[4];
    float  scale;

    // prologue: load tile kt=0
    #pragma unroll
    for (int j = 0; j < 8; ++j) ax[j] = xp[j];
    #pragma unroll
    for (int q = 0; q < 4; ++q) bx[q] = bp[q];
    scale = sp[0];

    f32x4 acc[4][4];
    #pragma unroll
    for (int mi = 0; mi < 4; ++mi)
        #pragma unroll
        for (int ni = 0; ni < 4; ++ni)
            acc[mi][ni] = (f32x4){0.f, 0.f, 0.f, 0.f};

    const int lane = tid & 63;
    const int wid  = tid >> 6;
    const int wm0  = (wid >> 1) * 64;   // wave's M sub-tile
    const int wn0  = (wid & 1) * 64;    // wave's N sub-tile
    const int fr   = lane & 15;         // fragment row/col
    const int fg   = lane >> 4;         // k-group 0..3

    __syncthreads();   // LUT visible

    for (int kt = 0; kt < NSTEP; ++kt) {
        // ---- stage A: 32 f32 -> 32 bf16 -> 4 swizzled 16B slots ----
        #pragma unroll
        for (int j = 0; j < 4; ++j) {
            float4 f0 = ax[2 * j], f1 = ax[2 * j + 1];
            uint4 v;
            v.x = f2bf(f0.x) | (f2bf(f0.y) << 16);
            v.y = f2bf(f0.z) | (f2bf(f0.w) << 16);
            v.z = f2bf(f1.x) | (f2bf(f1.y) << 16);
            v.w = f2bf(f1.z) | (f2bf(f1.w) << 16);
            lsA[(r * 8 + h * 4 + j) ^ (r & 7)] = v;
        }
        // ---- stage B: 16 packed bytes -> 32 dequant bf16 -> 4 slots ----
        #pragma unroll
        for (int q = 0; q < 4; ++q) {
            uint4 p = bx[q];
            float2 d0 = lut[p.x & 255];
            float2 d1 = lut[p.y & 255];
            float2 d2 = lut[p.z & 255];
            float2 d3 = lut[p.w & 255];
            uint4 v;
            v.x = f2bf(d0.x * scale) | (f2bf(d0.y * scale) << 16);
            v.y = f2bf(d1.x * scale) | (f2bf(d1.y * scale) << 16);
            v.z = f2bf(d2.x * scale) | (f2bf(d2.y * scale) << 16);
            v.w = f2bf(d3.x * scale) | (f2bf(d3.y * scale) << 16);
            lsB[(r * 8 + h * 4 + q) ^ (r & 7)] = v;
        }
        __syncthreads();

        // issue next tile's global loads (latency hides under MFMA)
        if (kt + 1 < NSTEP) {
            #pragma unroll
            for (int j = 0; j < 8; ++j) ax[j] = xp[(kt + 1) * 16 + j];
            #pragma unroll
            for (int q = 0; q < 4; ++q) bx[q] = bp[(kt + 1) * 8 + q];
            scale = sp[(kt + 1) * 2];
        }

        // ---- MFMA: 2 K-slices of 32, 4x4 fragments ----
        #pragma unroll
        for (int kk = 0; kk < 2; ++kk) {
            bf16x8 af[4], bfr[4];
            #pragma unroll
            for (int mi = 0; mi < 4; ++mi) {
                int row = wm0 + mi * 16 + fr;
                af[mi] = __builtin_bit_cast(bf16x8, lsA[(row * 8 + kk * 4 + fg) ^ (row & 7)]);
            }
            #pragma unroll
            for (int ni = 0; ni < 4; ++ni) {
                int row = wn0 + ni * 16 + fr;
                bfr[ni] = __builtin_bit_cast(bf16x8, lsB[(row * 8 + kk * 4 + fg) ^ (row & 7)]);
            }
            #pragma unroll
            for (int mi = 0; mi < 4; ++mi)
                #pragma unroll
                for (int ni = 0; ni < 4; ++ni)
                    acc[mi][ni] = __builtin_amdgcn_mfma_f32_16x16x32_bf16(
                        af[mi], bfr[ni], acc[mi][ni], 0, 0, 0);
        }

        __syncthreads();   // all frag reads done before next store
    }

    // ---- epilogue: bias + tanh-GELU, f32 store ----
    #pragma unroll
    for (int mi = 0; mi < 4; ++mi) {
        int row = bm0 + wm0 + mi * 16 + fg * 4;
        #pragma unroll
        for (int ni = 0; ni < 4; ++ni) {
            int col = bn0 + wn0 + ni * 16 + fr;
            float bv = bias[col];
            float* op = out + (size_t)row * N_DIM + col;
            #pragma unroll
            for (int q = 0; q < 4; ++q) {
                float v = acc[mi][ni][q] + bv;
                op[(size_t)q * N_DIM] = gelu_tanh(v);
            }
        }
    }
}

extern "C" void kernel_launch(void* const* d_in, const int* in_sizes, int n_in,
                              void* d_out, int out_size, void* d_ws, size_t ws_size,
                              hipStream_t stream) {
    const float* x     = (const float*)d_in[0];
    const int*   wp    = (const int*)d_in[1];
    const float* wsc   = (const float*)d_in[2];
    const float* bias  = (const float*)d_in[3];
    float*       out   = (float*)d_out;
    (void)in_sizes; (void)n_in; (void)d_ws; (void)ws_size; (void)out_size;

    dim3 grid(N_DIM / TILE_N, M_DIM / TILE_M);   // 128 x 16
    nvfp4_gemm<<<grid, 256, 0, stream>>>(x, wp, wsc, bias, out);
}

// Round 2
// 398.380 us; speedup vs baseline: 1.7489x; 1.7489x over previous
//
#include <hip/hip_runtime.h>
#include <hip/hip_bf16.h>

typedef short bf16x8 __attribute__((ext_vector_type(8)));
typedef float f32x4 __attribute__((ext_vector_type(4)));

#define K_DIM 4096
#define N_DIM 16384
#define M_DIM 2048
#define BM 128
#define BN 128
#define BK 64
#define KSTEPS (K_DIM / BK)            // 64
#define TILE_BYTES (BM * BK * 2)       // 16384 B per (tile,kstep) stripe
#define WSB_BYTES ((size_t)N_DIM * K_DIM * 2)   // 134217728
#define WSA_BYTES ((size_t)M_DIM * K_DIM * 2)   // 16777216

__device__ __forceinline__ unsigned f2bf(float f) {
    unsigned u = __builtin_bit_cast(unsigned, f);
    u += 0x7FFFu + ((u >> 16) & 1u);
    return u >> 16;   // RNE, inputs finite
}

// NVFP4 e2m1 nibble -> f32 (branchless bit construction), times scale
__device__ __forceinline__ float dec4(unsigned c, float s) {
    unsigned mag = c & 7u;
    unsigned u = (mag >= 2u) ? ((((mag >> 1) + 126u) << 23) | ((mag & 1u) << 22))
                             : (mag == 1u ? 0x3F000000u : 0u);
    u |= (c & 8u) << 28;   // sign
    return __builtin_bit_cast(float, u) * s;
}

__device__ __forceinline__ float gelu_tanh(float v) {
    float c = v + 0.044715f * v * v * v;
    float t = tanhf(0.7978845608028654f * c);
    return 0.5f * v * (1.0f + t);
}

// ---------------- Pass 1a: dequant W -> bf16, tiled + pre-swizzled ----------------
// thread -> one 16B output chunk (8 weights along K), 4 int32 packed bytes in.
__global__ __launch_bounds__(256) void dequant_w(const int* __restrict__ wp,
                                                 const float* __restrict__ wsc,
                                                 unsigned char* __restrict__ dst) {
    int t = blockIdx.x * 256 + threadIdx.x;      // 0 .. N*K/8-1 = 8388607
    int n = t >> 9;                              // K/8 = 512 chunks per row
    int ck = t & 511;
    int kstep = ck >> 3, s = ck & 7;
    int nt = n >> 7, r = n & 127;

    const int4 p4 = *reinterpret_cast<const int4*>(wp + (size_t)n * (K_DIM / 2) + kstep * 32 + s * 4);
    float scale = wsc[(size_t)n * (K_DIM / 32) + kstep * 2 + (s >> 2)];

    const int pv[4] = {p4.x, p4.y, p4.z, p4.w};
    unsigned o[8];
    #pragma unroll
    for (int j = 0; j < 4; ++j) {
        unsigned b = (unsigned)pv[j] & 255u;
        o[2 * j]     = f2bf(dec4(b & 15u, scale));         // even K
        o[2 * j + 1] = f2bf(dec4((b >> 4) & 15u, scale));  // odd K
    }
    uint4 v;
    v.x = o[0] | (o[1] << 16);
    v.y = o[2] | (o[3] << 16);
    v.z = o[4] | (o[5] << 16);
    v.w = o[6] | (o[7] << 16);

    size_t off = (size_t)(nt * KSTEPS + kstep) * TILE_BYTES
               + (size_t)r * 128 + (size_t)((s ^ (r & 7)) << 4);
    *reinterpret_cast<uint4*>(dst + off) = v;
}

// ---------------- Pass 1b: x f32 -> bf16, tiled + pre-swizzled ----------------
__global__ __launch_bounds__(256) void conv_x(const float* __restrict__ x,
                                              unsigned char* __restrict__ dst) {
    int t = blockIdx.x * 256 + threadIdx.x;      // 0 .. M*K/8-1 = 1048575
    int m = t >> 9;
    int ck = t & 511;
    int kstep = ck >> 3, s = ck & 7;
    int mt = m >> 7, r = m & 127;

    const float4* xp = reinterpret_cast<const float4*>(x + (size_t)m * K_DIM + kstep * 64 + s * 8);
    float4 a = xp[0], b = xp[1];
    uint4 v;
    v.x = f2bf(a.x) | (f2bf(a.y) << 16);
    v.y = f2bf(a.z) | (f2bf(a.w) << 16);
    v.z = f2bf(b.x) | (f2bf(b.y) << 16);
    v.w = f2bf(b.z) | (f2bf(b.w) << 16);

    size_t off = (size_t)(mt * KSTEPS + kstep) * TILE_BYTES
               + (size_t)r * 128 + (size_t)((s ^ (r & 7)) << 4);
    *reinterpret_cast<uint4*>(dst + off) = v;
}

// ---------------- Pass 2: bf16 GEMM (m97 structure: global_load_lds + swz reads) --------
__global__ __launch_bounds__(256, 4) void gemm_bf16(
    const unsigned char* __restrict__ wsA,
    const unsigned char* __restrict__ wsB,
    const float* __restrict__ bias,
    float* __restrict__ out)
{
    __shared__ unsigned char lsA[TILE_BYTES];
    __shared__ unsigned char lsB[TILE_BYTES];

    // XCD-chunked bijective swizzle (2048 % 8 == 0), m-minor within chunk -> B reuse in L2
    int id = blockIdx.x;
    int wg = (id & 7) * 256 + (id >> 3);
    int nt = wg >> 4;      // 0..127
    int mt = wg & 15;      // 0..15

    const int tid = threadIdx.x;
    const int lane = tid & 63;
    const int w = tid >> 6;
    const int wm0 = (w >> 1) * 64;
    const int wn0 = (w & 1) * 64;
    const int fr = lane & 15;
    const int fg = lane >> 4;

    const unsigned char* gA = wsA + (size_t)mt * KSTEPS * TILE_BYTES;
    const unsigned char* gB = wsB + (size_t)nt * KSTEPS * TILE_BYTES;

    f32x4 acc[4][4];
    #pragma unroll
    for (int mi = 0; mi < 4; ++mi)
        #pragma unroll
        for (int ni = 0; ni < 4; ++ni)
            acc[mi][ni] = (f32x4){0.f, 0.f, 0.f, 0.f};

    for (int kt = 0; kt < KSTEPS; ++kt) {
        const unsigned char* a_t = gA + (size_t)kt * TILE_BYTES;
        const unsigned char* b_t = gB + (size_t)kt * TILE_BYTES;
        #pragma unroll
        for (int j = 0; j < 4; ++j) {
            int c = w * 4 + j;   // wave-uniform chunk 0..15, 1 KiB each
            __builtin_amdgcn_global_load_lds(
                (const __attribute__((address_space(1))) unsigned int*)(a_t + (c << 10) + lane * 16),
                (__attribute__((address_space(3))) unsigned int*)(lsA + (c << 10)),
                16, 0, 0);
            __builtin_amdgcn_global_load_lds(
                (const __attribute__((address_space(1))) unsigned int*)(b_t + (c << 10) + lane * 16),
                (__attribute__((address_space(3))) unsigned int*)(lsB + (c << 10)),
                16, 0, 0);
        }
        __syncthreads();

        #pragma unroll
        for (int kk = 0; kk < 2; ++kk) {
            bf16x8 af[4], bfr[4];
            #pragma unroll
            for (int mi = 0; mi < 4; ++mi) {
                int row = wm0 + mi * 16 + fr;
                af[mi] = *reinterpret_cast<const bf16x8*>(
                    lsA + row * 128 + (((kk * 4 + fg) ^ (row & 7)) << 4));
            }
            #pragma unroll
            for (int ni = 0; ni < 4; ++ni) {
                int row = wn0 + ni * 16 + fr;
                bfr[ni] = *reinterpret_cast<const bf16x8*>(
                    lsB + row * 128 + (((kk * 4 + fg) ^ (row & 7)) << 4));
            }
            #pragma unroll
            for (int mi = 0; mi < 4; ++mi)
                #pragma unroll
                for (int ni = 0; ni < 4; ++ni)
                    acc[mi][ni] = __builtin_amdgcn_mfma_f32_16x16x32_bf16(
                        af[mi], bfr[ni], acc[mi][ni], 0, 0, 0);
        }
        __syncthreads();
    }

    const int bm0 = mt * BM, bn0 = nt * BN;
    #pragma unroll
    for (int mi = 0; mi < 4; ++mi) {
        int row = bm0 + wm0 + mi * 16 + fg * 4;
        #pragma unroll
        for (int ni = 0; ni < 4; ++ni) {
            int col = bn0 + wn0 + ni * 16 + fr;
            float bv = bias[col];
            float* op = out + (size_t)row * N_DIM + col;
            #pragma unroll
            for (int q = 0; q < 4; ++q) {
                float v = acc[mi][ni][q] + bv;
                op[(size_t)q * N_DIM] = gelu_tanh(v);
            }
        }
    }
}

// ---------------- Fallback: round-1 fused kernel (used only if ws too small) ----------
__global__ __launch_bounds__(256, 2) void nvfp4_gemm(
    const float* __restrict__ x,
    const int*   __restrict__ wp,
    const float* __restrict__ wscale,
    const float* __restrict__ bias,
    float*       __restrict__ out)
{
    __shared__ uint4  lsA[BM * 8];
    __shared__ uint4  lsB[BN * 8];
    __shared__ float2 lut[256];

    const int tid = threadIdx.x;
    {
        static const float dectab[16] = {0.f, 0.5f, 1.f, 1.5f, 2.f, 3.f, 4.f, 6.f,
                                         -0.f,-0.5f,-1.f,-1.5f,-2.f,-3.f,-4.f,-6.f};
        lut[tid] = make_float2(dectab[tid & 15], dectab[(tid >> 4) & 15]);
    }

    const int bn0 = blockIdx.x * BN;
    const int bm0 = blockIdx.y * BM;
    const int r = tid >> 1;
    const int h = tid & 1;

    const float4* xp = reinterpret_cast<const float4*>(x + (size_t)(bm0 + r) * K_DIM) + h * 8;
    const uint4*  bp = reinterpret_cast<const uint4*>(wp + (size_t)(bn0 + r) * (K_DIM / 2)) + h * 4;
    const float*  sp = wscale + (size_t)(bn0 + r) * (K_DIM / 32) + h;

    float4 ax[8];
    uint4  bx[4];
    float  scale;
    #pragma unroll
    for (int j = 0; j < 8; ++j) ax[j] = xp[j];
    #pragma unroll
    for (int q = 0; q < 4; ++q) bx[q] = bp[q];
    scale = sp[0];

    f32x4 acc[4][4];
    #pragma unroll
    for (int mi = 0; mi < 4; ++mi)
        #pragma unroll
        for (int ni = 0; ni < 4; ++ni)
            acc[mi][ni] = (f32x4){0.f, 0.f, 0.f, 0.f};

    const int lane = tid & 63;
    const int wid  = tid >> 6;
    const int wm0  = (wid >> 1) * 64;
    const int wn0  = (wid & 1) * 64;
    const int fr   = lane & 15;
    const int fg   = lane >> 4;

    __syncthreads();

    for (int kt = 0; kt < KSTEPS; ++kt) {
        #pragma unroll
        for (int j = 0; j < 4; ++j) {
            float4 f0 = ax[2 * j], f1 = ax[2 * j + 1];
            uint4 v;
            v.x = f2bf(f0.x) | (f2bf(f0.y) << 16);
            v.y = f2bf(f0.z) | (f2bf(f0.w) << 16);
            v.z = f2bf(f1.x) | (f2bf(f1.y) << 16);
            v.w = f2bf(f1.z) | (f2bf(f1.w) << 16);
            lsA[(r * 8 + h * 4 + j) ^ (r & 7)] = v;
        }
        #pragma unroll
        for (int q = 0; q < 4; ++q) {
            uint4 p = bx[q];
            float2 d0 = lut[p.x & 255];
            float2 d1 = lut[p.y & 255];
            float2 d2 = lut[p.z & 255];
            float2 d3 = lut[p.w & 255];
            uint4 v;
            v.x = f2bf(d0.x * scale) | (f2bf(d0.y * scale) << 16);
            v.y = f2bf(d1.x * scale) | (f2bf(d1.y * scale) << 16);
            v.z = f2bf(d2.x * scale) | (f2bf(d2.y * scale) << 16);
            v.w = f2bf(d3.x * scale) | (f2bf(d3.y * scale) << 16);
            lsB[(r * 8 + h * 4 + q) ^ (r & 7)] = v;
        }
        __syncthreads();

        if (kt + 1 < KSTEPS) {
            #pragma unroll
            for (int j = 0; j < 8; ++j) ax[j] = xp[(kt + 1) * 16 + j];
            #pragma unroll
            for (int q = 0; q < 4; ++q) bx[q] = bp[(kt + 1) * 8 + q];
            scale = sp[(kt + 1) * 2];
        }

        #pragma unroll
        for (int kk = 0; kk < 2; ++kk) {
            bf16x8 af[4], bfr[4];
            #pragma unroll
            for (int mi = 0; mi < 4; ++mi) {
                int row = wm0 + mi * 16 + fr;
                af[mi] = __builtin_bit_cast(bf16x8, lsA[(row * 8 + kk * 4 + fg) ^ (row & 7)]);
            }
            #pragma unroll
            for (int ni = 0; ni < 4; ++ni) {
                int row = wn0 + ni * 16 + fr;
                bfr[ni] = __builtin_bit_cast(bf16x8, lsB[(row * 8 + kk * 4 + fg) ^ (row & 7)]);
            }
            #pragma unroll
            for (int mi = 0; mi < 4; ++mi)
                #pragma unroll
                for (int ni = 0; ni < 4; ++ni)
                    acc[mi][ni] = __builtin_amdgcn_mfma_f32_16x16x32_bf16(
                        af[mi], bfr[ni], acc[mi][ni], 0, 0, 0);
        }
        __syncthreads();
    }

    #pragma unroll
    for (int mi = 0; mi < 4; ++mi) {
        int row = bm0 + wm0 + mi * 16 + fg * 4;
        #pragma unroll
        for (int ni = 0; ni < 4; ++ni) {
            int col = bn0 + wn0 + ni * 16 + fr;
            float bv = bias[col];
            float* op = out + (size_t)row * N_DIM + col;
            #pragma unroll
            for (int q = 0; q < 4; ++q) {
                float v = acc[mi][ni][q] + bv;
                op[(size_t)q * N_DIM] = gelu_tanh(v);
            }
        }
    }
}

extern "C" void kernel_launch(void* const* d_in, const int* in_sizes, int n_in,
                              void* d_out, int out_size, void* d_ws, size_t ws_size,
                              hipStream_t stream) {
    const float* x    = (const float*)d_in[0];
    const int*   wp   = (const int*)d_in[1];
    const float* wsc  = (const float*)d_in[2];
    const float* bias = (const float*)d_in[3];
    float*       out  = (float*)d_out;
    (void)in_sizes; (void)n_in; (void)out_size;

    if (ws_size >= WSB_BYTES + WSA_BYTES) {
        unsigned char* wsB = (unsigned char*)d_ws;
        unsigned char* wsA = wsB + WSB_BYTES;
        dequant_w<<<(N_DIM * (K_DIM / 8)) / 256, 256, 0, stream>>>(wp, wsc, wsB);
        conv_x<<<(M_DIM * (K_DIM / 8)) / 256, 256, 0, stream>>>(x, wsA);
        gemm_bf16<<<(M_DIM / BM) * (N_DIM / BN), 256, 0, stream>>>(wsA, wsB, bias, out);
    } else {
        dim3 grid(N_DIM / BN, M_DIM / BM);
        nvfp4_gemm<<<grid, 256, 0, stream>>>(x, wp, wsc, bias, out);
    }
}

// Round 3
// 322.267 us; speedup vs baseline: 2.1619x; 1.2362x over previous
//
#include <hip/hip_runtime.h>
#include <hip/hip_bf16.h>

typedef short bf16x8 __attribute__((ext_vector_type(8)));
typedef float f32x4 __attribute__((ext_vector_type(4)));

#define K_DIM 4096
#define N_DIM 16384
#define M_DIM 2048
#define STRIPE 16384                       // bytes per (tile128, kstep64) stripe in ws
#define TSTRIDE (64 * STRIPE)              // bytes per 128-row tile (1 MiB)
#define WSB_BYTES ((size_t)N_DIM * K_DIM * 2)   // 134217728
#define WSA_BYTES ((size_t)M_DIM * K_DIM * 2)   // 16777216

__device__ __forceinline__ unsigned f2bf(float f) {
    unsigned u = __builtin_bit_cast(unsigned, f);
    u += 0x7FFFu + ((u >> 16) & 1u);
    return u >> 16;   // RNE, inputs finite
}

// NVFP4 e2m1 nibble -> f32 (branchless), times scale
__device__ __forceinline__ float dec4(unsigned c, float s) {
    unsigned mag = c & 7u;
    unsigned u = (mag >= 2u) ? ((((mag >> 1) + 126u) << 23) | ((mag & 1u) << 22))
                             : (mag == 1u ? 0x3F000000u : 0u);
    u |= (c & 8u) << 28;   // sign
    return __builtin_bit_cast(float, u) * s;
}

__device__ __forceinline__ float gelu_tanh(float v) {
    float c = v + 0.044715f * v * v * v;
    float t = tanhf(0.7978845608028654f * c);
    return 0.5f * v * (1.0f + t);
}

// ---------------- Pass 1a: dequant W -> bf16, tiled + pre-swizzled (unchanged) ----------
__global__ __launch_bounds__(256) void dequant_w(const int* __restrict__ wp,
                                                 const float* __restrict__ wsc,
                                                 unsigned char* __restrict__ dst) {
    int t = blockIdx.x * 256 + threadIdx.x;      // 0 .. N*K/8-1
    int n = t >> 9;                              // K/8 = 512 chunks per row
    int ck = t & 511;
    int kstep = ck >> 3, s = ck & 7;
    int nt = n >> 7, r = n & 127;

    const int4 p4 = *reinterpret_cast<const int4*>(wp + (size_t)n * (K_DIM / 2) + kstep * 32 + s * 4);
    float scale = wsc[(size_t)n * (K_DIM / 32) + kstep * 2 + (s >> 2)];

    const int pv[4] = {p4.x, p4.y, p4.z, p4.w};
    unsigned o[8];
    #pragma unroll
    for (int j = 0; j < 4; ++j) {
        unsigned b = (unsigned)pv[j] & 255u;
        o[2 * j]     = f2bf(dec4(b & 15u, scale));
        o[2 * j + 1] = f2bf(dec4((b >> 4) & 15u, scale));
    }
    uint4 v;
    v.x = o[0] | (o[1] << 16);
    v.y = o[2] | (o[3] << 16);
    v.z = o[4] | (o[5] << 16);
    v.w = o[6] | (o[7] << 16);

    size_t off = (size_t)(nt * 64 + kstep) * STRIPE
               + (size_t)r * 128 + (size_t)((s ^ (r & 7)) << 4);
    *reinterpret_cast<uint4*>(dst + off) = v;
}

// ---------------- Pass 1b: x f32 -> bf16, tiled + pre-swizzled (unchanged) --------------
__global__ __launch_bounds__(256) void conv_x(const float* __restrict__ x,
                                              unsigned char* __restrict__ dst) {
    int t = blockIdx.x * 256 + threadIdx.x;      // 0 .. M*K/8-1
    int m = t >> 9;
    int ck = t & 511;
    int kstep = ck >> 3, s = ck & 7;
    int mt = m >> 7, r = m & 127;

    const float4* xp = reinterpret_cast<const float4*>(x + (size_t)m * K_DIM + kstep * 64 + s * 8);
    float4 a = xp[0], b = xp[1];
    uint4 v;
    v.x = f2bf(a.x) | (f2bf(a.y) << 16);
    v.y = f2bf(a.z) | (f2bf(a.w) << 16);
    v.z = f2bf(b.x) | (f2bf(b.y) << 16);
    v.w = f2bf(b.z) | (f2bf(b.w) << 16);

    size_t off = (size_t)(mt * 64 + kstep) * STRIPE
               + (size_t)r * 128 + (size_t)((s ^ (r & 7)) << 4);
    *reinterpret_cast<uint4*>(dst + off) = v;
}

// ---------------- Pass 2: 256^2 bf16 GEMM, ring-4 counted-vmcnt pipeline ----------------
// BK=32, 512 threads (8 waves, 2M x 4N), per-wave 128x64 output.
// LDS: 4 ring slots x (A 16 KiB + B 16 KiB) = 128 KiB.
// Tile t reads slot t&3; staging for tile t+3 issued during tile t (slot free since
// end of tile t-1's barrier). Boundary: s_waitcnt vmcnt(8) (2 tiles in flight) + raw
// s_barrier -- never drains to 0 in the main loop (T4).

__global__ __launch_bounds__(512, 2) void gemm_bf16_256(
    const unsigned char* __restrict__ wsA,
    const unsigned char* __restrict__ wsB,
    const float* __restrict__ bias,
    float* __restrict__ out)
{
    __shared__ unsigned char lds[131072];   // [0,64K) = A slots, [64K,128K) = B slots

    // XCD-chunked bijective swizzle: 512 wgs, 64 per XCD chunk covering MT 0..7 x NT 0..7
    int id = blockIdx.x;
    int wg = (id & 7) * 64 + (id >> 3);
    int MT = wg & 7;        // 0..7
    int NT = wg >> 3;       // 0..63

    const int tid  = threadIdx.x;
    const int lane = tid & 63;
    const int w    = tid >> 6;
    const int wm   = w >> 2;     // 0..1
    const int wn   = w & 3;      // 0..3
    const int fr   = lane & 15;
    const int fg   = lane >> 4;  // k-quarter 0..3 within BK=32

    const unsigned char* gA = wsA + (size_t)(2 * MT) * TSTRIDE;
    const unsigned char* gB = wsB + (size_t)(2 * NT) * TSTRIDE;

    // ds_read byte addresses within a 16 KiB slot (row-pair lines: 128 B = rows 2L,2L+1)
    int addrA[8];
    #pragma unroll
    for (int mi = 0; mi < 8; ++mi) {
        int row = wm * 128 + mi * 16 + fr;
        int L = row >> 1;
        addrA[mi] = L * 128 + (((((row & 1) << 2) | fg) ^ (L & 7)) << 4);
    }
    int addrB[4];
    #pragma unroll
    for (int ni = 0; ni < 4; ++ni) {
        int row = wn * 64 + ni * 16 + fr;
        int L = row >> 1;
        addrB[ni] = L * 128 + (((((row & 1) << 2) | fg) ^ (L & 7)) << 4);
    }

    // staging source offsets: lane covers LDS (L = c*8 + lane/8, p = lane&7);
    // content there must be ws logical (row = 2L+h, k-quarter fg), h*4+fg = p^(L&7),
    // at ws stripe physical slot ((kb*4+fg) ^ (row&7)).
    int offST[2][2];
    #pragma unroll
    for (int j = 0; j < 2; ++j) {
        int c = w * 2 + j;
        int L = c * 8 + (lane >> 3);
        int p = lane & 7;
        int sl = p ^ (L & 7);
        int h = sl >> 2, fgs = sl & 3;
        int row = 2 * L + h;
        #pragma unroll
        for (int kb = 0; kb < 2; ++kb)
            offST[j][kb] = (row >> 7) * TSTRIDE + (row & 127) * 128
                         + ((((kb << 2) | fgs) ^ (row & 7)) << 4);
    }

#define GLDS(SRC, DOFF) __builtin_amdgcn_global_load_lds(                          \
        (const __attribute__((address_space(1))) unsigned int*)(SRC),              \
        (__attribute__((address_space(3))) unsigned int*)(&lds[DOFF]), 16, 0, 0)

#define STAGE_A(KSOFF, KB, SLOT) do {                                              \
        GLDS(gA + (KSOFF) + offST[0][KB], ((SLOT) << 14) + (w * 2 + 0) * 1024);    \
        GLDS(gA + (KSOFF) + offST[1][KB], ((SLOT) << 14) + (w * 2 + 1) * 1024);    \
    } while (0)
#define STAGE_B(KSOFF, KB, SLOT) do {                                              \
        GLDS(gB + (KSOFF) + offST[0][KB], 65536 + ((SLOT) << 14) + (w * 2 + 0) * 1024); \
        GLDS(gB + (KSOFF) + offST[1][KB], 65536 + ((SLOT) << 14) + (w * 2 + 1) * 1024); \
    } while (0)

    f32x4 acc[8][4];
    #pragma unroll
    for (int mi = 0; mi < 8; ++mi)
        #pragma unroll
        for (int ni = 0; ni < 4; ++ni)
            acc[mi][ni] = (f32x4){0.f, 0.f, 0.f, 0.f};

    // prologue: stage tiles 0,1,2 into slots 0,1,2 (12 loads/wave); drain tile 0.
    STAGE_A(0, 0, 0);        STAGE_B(0, 0, 0);
    STAGE_A(0, 1, 1);        STAGE_B(0, 1, 1);
    STAGE_A(STRIPE, 0, 2);   STAGE_B(STRIPE, 0, 2);
    asm volatile("s_waitcnt vmcnt(8)" ::: "memory");
    __builtin_amdgcn_sched_barrier(0);
    __builtin_amdgcn_s_barrier();
    __builtin_amdgcn_sched_barrier(0);

// one K-tile: 12 ds_read_b128, optional 4-load staging of tile t+3, 32 MFMA in two
// setprio clusters, counted-vmcnt boundary (VMN<0 = no boundary, last tile).
#define TILE_BODY(RSLOT, DO_STG, STKS, STKB, SSLOT, VMN) do {                      \
        const unsigned char* la = lds + ((RSLOT) << 14);                           \
        const unsigned char* lb = lds + 65536 + ((RSLOT) << 14);                   \
        bf16x8 bfr[4], af[4];                                                      \
        if (DO_STG) STAGE_A(STKS, STKB, SSLOT);                                    \
        _Pragma("unroll") for (int ni = 0; ni < 4; ++ni)                           \
            bfr[ni] = *reinterpret_cast<const bf16x8*>(lb + addrB[ni]);            \
        _Pragma("unroll") for (int mi = 0; mi < 4; ++mi)                           \
            af[mi] = *reinterpret_cast<const bf16x8*>(la + addrA[mi]);             \
        __builtin_amdgcn_s_setprio(1);                                             \
        _Pragma("unroll") for (int mi = 0; mi < 4; ++mi)                           \
            _Pragma("unroll") for (int ni = 0; ni < 4; ++ni)                       \
                acc[mi][ni] = __builtin_amdgcn_mfma_f32_16x16x32_bf16(             \
                    af[mi], bfr[ni], acc[mi][ni], 0, 0, 0);                        \
        __builtin_amdgcn_s_setprio(0);                                             \
        if (DO_STG) STAGE_B(STKS, STKB, SSLOT);                                    \
        _Pragma("unroll") for (int mi = 0; mi < 4; ++mi)                           \
            af[mi] = *reinterpret_cast<const bf16x8*>(la + addrA[4 + mi]);         \
        __builtin_amdgcn_s_setprio(1);                                             \
        _Pragma("unroll") for (int mi = 0; mi < 4; ++mi)                           \
            _Pragma("unroll") for (int ni = 0; ni < 4; ++ni)                       \
                acc[4 + mi][ni] = __builtin_amdgcn_mfma_f32_16x16x32_bf16(         \
                    af[mi], bfr[ni], acc[4 + mi][ni], 0, 0, 0);                    \
        __builtin_amdgcn_s_setprio(0);                                             \
        if ((VMN) >= 0) {                                                          \
            if ((VMN) == 8)      asm volatile("s_waitcnt vmcnt(8)" ::: "memory");  \
            else if ((VMN) == 4) asm volatile("s_waitcnt vmcnt(4)" ::: "memory");  \
            else                 asm volatile("s_waitcnt vmcnt(0)" ::: "memory");  \
            __builtin_amdgcn_sched_barrier(0);                                     \
            __builtin_amdgcn_s_barrier();                                          \
            __builtin_amdgcn_sched_barrier(0);                                     \
        }                                                                          \
    } while (0)

    // main loop: tiles t = 2tp, 2tp+1 for tp = 0..61 (t <= 123), full stage + vmcnt(8)
    for (int tp = 0; tp < 62; ++tp) {
        const int scur = (tp & 1) << 1;              // slot of tile 2tp
        const int ks1 = (tp + 1) * STRIPE;           // stage tile 2tp+3 (kb=1)
        const int ks2 = (tp + 2) * STRIPE;           // stage tile 2tp+4 (kb=0)
        TILE_BODY(scur,     1, ks1, 1, scur ^ 3, 8);
        TILE_BODY(scur ^ 1, 1, ks2, 0, scur,     8);
    }
    // tail: tiles 124..127 in slots 0..3; stage only 127; drain 8 -> 4 -> 0.
    TILE_BODY(0, 1, 63 * STRIPE, 1, 3, 8);
    TILE_BODY(1, 0, 0, 0, 0, 4);
    TILE_BODY(2, 0, 0, 0, 0, 0);
    TILE_BODY(3, 0, 0, 0, 0, -1);

    // epilogue: bias + tanh-GELU, f32 stores
    const int bm0 = MT * 256, bn0 = NT * 256;
    #pragma unroll
    for (int mi = 0; mi < 8; ++mi) {
        int row = bm0 + wm * 128 + mi * 16 + fg * 4;
        #pragma unroll
        for (int ni = 0; ni < 4; ++ni) {
            int col = bn0 + wn * 64 + ni * 16 + fr;
            float bv = bias[col];
            float* op = out + (size_t)row * N_DIM + col;
            #pragma unroll
            for (int q = 0; q < 4; ++q) {
                float v = acc[mi][ni][q] + bv;
                op[(size_t)q * N_DIM] = gelu_tanh(v);
            }
        }
    }
#undef TILE_BODY
#undef STAGE_A
#undef STAGE_B
#undef GLDS
}

// ---------------- Fallback: round-1 fused kernel (used only if ws too small) ------------
__global__ __launch_bounds__(256, 2) void nvfp4_gemm(
    const float* __restrict__ x,
    const int*   __restrict__ wp,
    const float* __restrict__ wscale,
    const float* __restrict__ bias,
    float* __restrict__ out)
{
    __shared__ uint4  lsA[128 * 8];
    __shared__ uint4  lsB[128 * 8];
    __shared__ float2 lut[256];

    const int tid = threadIdx.x;
    {
        static const float dectab[16] = {0.f, 0.5f, 1.f, 1.5f, 2.f, 3.f, 4.f, 6.f,
                                         -0.f,-0.5f,-1.f,-1.5f,-2.f,-3.f,-4.f,-6.f};
        lut[tid] = make_float2(dectab[tid & 15], dectab[(tid >> 4) & 15]);
    }

    const int bn0 = blockIdx.x * 128;
    const int bm0 = blockIdx.y * 128;
    const int r = tid >> 1;
    const int h = tid & 1;

    const float4* xp = reinterpret_cast<const float4*>(x + (size_t)(bm0 + r) * K_DIM) + h * 8;
    const uint4*  bp = reinterpret_cast<const uint4*>(wp + (size_t)(bn0 + r) * (K_DIM / 2)) + h * 4;
    const float*  sp = wscale + (size_t)(bn0 + r) * (K_DIM / 32) + h;

    float4 ax[8];
    uint4  bx[4];
    float  scale;
    #pragma unroll
    for (int j = 0; j < 8; ++j) ax[j] = xp[j];
    #pragma unroll
    for (int q = 0; q < 4; ++q) bx[q] = bp[q];
    scale = sp[0];

    f32x4 acc[4][4];
    #pragma unroll
    for (int mi = 0; mi < 4; ++mi)
        #pragma unroll
        for (int ni = 0; ni < 4; ++ni)
            acc[mi][ni] = (f32x4){0.f, 0.f, 0.f, 0.f};

    const int lane = tid & 63;
    const int wid  = tid >> 6;
    const int wm0  = (wid >> 1) * 64;
    const int wn0  = (wid & 1) * 64;
    const int fr   = lane & 15;
    const int fg   = lane >> 4;

    __syncthreads();

    for (int kt = 0; kt < 64; ++kt) {
        #pragma unroll
        for (int j = 0; j < 4; ++j) {
            float4 f0 = ax[2 * j], f1 = ax[2 * j + 1];
            uint4 v;
            v.x = f2bf(f0.x) | (f2bf(f0.y) << 16);
            v.y = f2bf(f0.z) | (f2bf(f0.w) << 16);
            v.z = f2bf(f1.x) | (f2bf(f1.y) << 16);
            v.w = f2bf(f1.z) | (f2bf(f1.w) << 16);
            lsA[(r * 8 + h * 4 + j) ^ (r & 7)] = v;
        }
        #pragma unroll
        for (int q = 0; q < 4; ++q) {
            uint4 p = bx[q];
            float2 d0 = lut[p.x & 255];
            float2 d1 = lut[p.y & 255];
            float2 d2 = lut[p.z & 255];
            float2 d3 = lut[p.w & 255];
            uint4 v;
            v.x = f2bf(d0.x * scale) | (f2bf(d0.y * scale) << 16);
            v.y = f2bf(d1.x * scale) | (f2bf(d1.y * scale) << 16);
            v.z = f2bf(d2.x * scale) | (f2bf(d2.y * scale) << 16);
            v.w = f2bf(d3.x * scale) | (f2bf(d3.y * scale) << 16);
            lsB[(r * 8 + h * 4 + q) ^ (r & 7)] = v;
        }
        __syncthreads();

        if (kt + 1 < 64) {
            #pragma unroll
            for (int j = 0; j < 8; ++j) ax[j] = xp[(kt + 1) * 16 + j];
            #pragma unroll
            for (int q = 0; q < 4; ++q) bx[q] = bp[(kt + 1) * 8 + q];
            scale = sp[(kt + 1) * 2];
        }

        #pragma unroll
        for (int kk = 0; kk < 2; ++kk) {
            bf16x8 af[4], bfr[4];
            #pragma unroll
            for (int mi = 0; mi < 4; ++mi) {
                int row = wm0 + mi * 16 + fr;
                af[mi] = __builtin_bit_cast(bf16x8, lsA[(row * 8 + kk * 4 + fg) ^ (row & 7)]);
            }
            #pragma unroll
            for (int ni = 0; ni < 4; ++ni) {
                int row = wn0 + ni * 16 + fr;
                bfr[ni] = __builtin_bit_cast(bf16x8, lsB[(row * 8 + kk * 4 + fg) ^ (row & 7)]);
            }
            #pragma unroll
            for (int mi = 0; mi < 4; ++mi)
                #pragma unroll
                for (int ni = 0; ni < 4; ++ni)
                    acc[mi][ni] = __builtin_amdgcn_mfma_f32_16x16x32_bf16(
                        af[mi], bfr[ni], acc[mi][ni], 0, 0, 0);
        }
        __syncthreads();
    }

    #pragma unroll
    for (int mi = 0; mi < 4; ++mi) {
        int row = bm0 + wm0 + mi * 16 + fg * 4;
        #pragma unroll
        for (int ni = 0; ni < 4; ++ni) {
            int col = bn0 + wn0 + ni * 16 + fr;
            float bv = bias[col];
            float* op = out + (size_t)row * N_DIM + col;
            #pragma unroll
            for (int q = 0; q < 4; ++q) {
                float v = acc[mi][ni][q] + bv;
                op[(size_t)q * N_DIM] = gelu_tanh(v);
            }
        }
    }
}

extern "C" void kernel_launch(void* const* d_in, const int* in_sizes, int n_in,
                              void* d_out, int out_size, void* d_ws, size_t ws_size,
                              hipStream_t stream) {
    const float* x    = (const float*)d_in[0];
    const int*   wp   = (const int*)d_in[1];
    const float* wsc  = (const float*)d_in[2];
    const float* bias = (const float*)d_in[3];
    float*       out  = (float*)d_out;
    (void)in_sizes; (void)n_in; (void)out_size;

    if (ws_size >= WSB_BYTES + WSA_BYTES) {
        unsigned char* wsB = (unsigned char*)d_ws;
        unsigned char* wsA = wsB + WSB_BYTES;
        dequant_w<<<(N_DIM * (K_DIM / 8)) / 256, 256, 0, stream>>>(wp, wsc, wsB);
        conv_x<<<(M_DIM * (K_DIM / 8)) / 256, 256, 0, stream>>>(x, wsA);
        gemm_bf16_256<<<(M_DIM / 256) * (N_DIM / 256), 512, 0, stream>>>(wsA, wsB, bias, out);
    } else {
        dim3 grid(N_DIM / 128, M_DIM / 128);
        nvfp4_gemm<<<grid, 256, 0, stream>>>(x, wp, wsc, bias, out);
    }
}